// Round 2
// baseline (8182.301 us; speedup 1.0000x reference)
//
#include <hip/hip_runtime.h>

#define N_ROWS 8192
#define D_IN   768
#define D_SAE  24576
#define K_TOP  32
#define C_SEL  40          // candidates selected before refinement
#define DELTA  5e-4f       // fp32 boundary-gap threshold that triggers fp64 refine

// ---------------- GEMM: z = relu((x - b_dec) @ W_enc + b_enc) ----------------
#define BM 128
#define BN 128
#define BK 16
#define LDSS (BM + 4)

__global__ __launch_bounds__(256)
void sae_encode_gemm(const float* __restrict__ x,
                     const float* __restrict__ W_enc,
                     const float* __restrict__ b_enc,
                     const float* __restrict__ b_dec,
                     float* __restrict__ z)
{
    __shared__ float As[BK][LDSS];
    __shared__ float Bs[BK][LDSS];

    const int tid  = threadIdx.x;
    const int bn   = blockIdx.x;
    const int bm   = blockIdx.y;
    const int row0 = bm * BM;
    const int col0 = bn * BN;

    const int tm = tid >> 4;
    const int tn = tid & 15;

    const int lm = tid >> 2;
    const int kq = tid & 3;
    const int lk = tid >> 5;
    const int nq = tid & 31;

    float acc[8][8];
#pragma unroll
    for (int i = 0; i < 8; ++i)
#pragma unroll
        for (int j = 0; j < 8; ++j) acc[i][j] = 0.f;

    for (int k0 = 0; k0 < D_IN; k0 += BK) {
#pragma unroll
        for (int h = 0; h < 2; ++h) {
            const int m = lm + h * 64;
            const float4 xa = *(const float4*)(&x[(size_t)(row0 + m) * D_IN + k0 + kq * 4]);
            const float4 bd = *(const float4*)(&b_dec[k0 + kq * 4]);
            As[kq * 4 + 0][m] = xa.x - bd.x;
            As[kq * 4 + 1][m] = xa.y - bd.y;
            As[kq * 4 + 2][m] = xa.z - bd.z;
            As[kq * 4 + 3][m] = xa.w - bd.w;
        }
#pragma unroll
        for (int h = 0; h < 2; ++h) {
            const int kk = lk + h * 8;
            const float4 wb = *(const float4*)(&W_enc[(size_t)(k0 + kk) * D_SAE + col0 + nq * 4]);
            *(float4*)(&Bs[kk][nq * 4]) = wb;
        }
        __syncthreads();

#pragma unroll
        for (int kk = 0; kk < BK; ++kk) {
            float a[8], b[8];
            *(float4*)(&a[0]) = *(const float4*)(&As[kk][tm * 4]);
            *(float4*)(&a[4]) = *(const float4*)(&As[kk][tm * 4 + 64]);
            *(float4*)(&b[0]) = *(const float4*)(&Bs[kk][tn * 4]);
            *(float4*)(&b[4]) = *(const float4*)(&Bs[kk][tn * 4 + 64]);
#pragma unroll
            for (int i = 0; i < 8; ++i)
#pragma unroll
                for (int j = 0; j < 8; ++j)
                    acc[i][j] = fmaf(a[i], b[j], acc[i][j]);
        }
        __syncthreads();
    }

    const float4 be0 = *(const float4*)(&b_enc[col0 + tn * 4]);
    const float4 be1 = *(const float4*)(&b_enc[col0 + 64 + tn * 4]);
#pragma unroll
    for (int i = 0; i < 8; ++i) {
        const int r = row0 + tm * 4 + (i & 3) + ((i >> 2) * 64);
        float4 v0, v1;
        v0.x = fmaxf(acc[i][0] + be0.x, 0.f);
        v0.y = fmaxf(acc[i][1] + be0.y, 0.f);
        v0.z = fmaxf(acc[i][2] + be0.z, 0.f);
        v0.w = fmaxf(acc[i][3] + be0.w, 0.f);
        v1.x = fmaxf(acc[i][4] + be1.x, 0.f);
        v1.y = fmaxf(acc[i][5] + be1.y, 0.f);
        v1.z = fmaxf(acc[i][6] + be1.z, 0.f);
        v1.w = fmaxf(acc[i][7] + be1.w, 0.f);
        const size_t off = (size_t)r * D_SAE + col0;
        *(float4*)(&z[off + tn * 4])      = v0;
        *(float4*)(&z[off + 64 + tn * 4]) = v1;
    }
}

// ------------- per-row: top-40 select, fp64 refine if boundary tight, sparsify, decode -------------
#define TB  256
#define QPT (D_SAE / 4 / TB)

__global__ __launch_bounds__(TB)
void sae_topk_decode(float* __restrict__ z,            // dense in, sparse out (same buffer)
                     const float* __restrict__ x,
                     const float* __restrict__ W_enc,
                     const float* __restrict__ b_enc,
                     const float* __restrict__ W_dec,
                     const float* __restrict__ b_dec,
                     float* __restrict__ x_rec)
{
    __shared__ float  zrow[D_SAE];         // 96 KB
    __shared__ float  xrow[D_IN];          // refine path
    __shared__ double cand[C_SEL];
    __shared__ float  wval[4];
    __shared__ int    widx[4];
    __shared__ float  selval[C_SEL];
    __shared__ int    selidx[C_SEL];

    const int row = blockIdx.x;
    const int t   = threadIdx.x;
    float* zr = z + (size_t)row * D_SAE;

#pragma unroll
    for (int i = 0; i < QPT; ++i) {
        const int q = t + i * TB;
        *(float4*)(&zrow[q * 4]) = *(const float4*)(&zr[q * 4]);
    }
    __syncthreads();

    const float NEG_INF = -__builtin_inff();

    float bv = NEG_INF; int bi = 0;
#pragma unroll
    for (int i = 0; i < QPT; ++i) {
        const int q = t + i * TB;
        const float4 v = *(const float4*)(&zrow[q * 4]);
        if (v.x > bv) { bv = v.x; bi = q * 4 + 0; }
        if (v.y > bv) { bv = v.y; bi = q * 4 + 1; }
        if (v.z > bv) { bv = v.z; bi = q * 4 + 2; }
        if (v.w > bv) { bv = v.w; bi = q * 4 + 3; }
    }

    for (int s = 0; s < C_SEL; ++s) {
        float wv = bv; int wi = bi;
#pragma unroll
        for (int off = 32; off > 0; off >>= 1) {
            const float ov = __shfl_xor(wv, off);
            const int   oi = __shfl_xor(wi, off);
            if (ov > wv || (ov == wv && oi < wi)) { wv = ov; wi = oi; }
        }
        const int w = t >> 6;
        if ((t & 63) == 0) { wval[w] = wv; widx[w] = wi; }
        __syncthreads();
        float gv = wval[0]; int gi = widx[0];
#pragma unroll
        for (int w2 = 1; w2 < 4; ++w2) {
            const float v2 = wval[w2]; const int i2 = widx[w2];
            if (v2 > gv || (v2 == gv && i2 < gi)) { gv = v2; gi = i2; }
        }
        if (t == 0) { selval[s] = gv; selidx[s] = gi; }
        if (((gi >> 2) & (TB - 1)) == t) {
            zrow[gi] = NEG_INF;
            bv = NEG_INF; bi = 0;
#pragma unroll
            for (int i = 0; i < QPT; ++i) {
                const int q = t + i * TB;
                const float4 v = *(const float4*)(&zrow[q * 4]);
                if (v.x > bv) { bv = v.x; bi = q * 4 + 0; }
                if (v.y > bv) { bv = v.y; bi = q * 4 + 1; }
                if (v.z > bv) { bv = v.z; bi = q * 4 + 2; }
                if (v.w > bv) { bv = v.w; bi = q * 4 + 3; }
            }
        }
        __syncthreads();
    }

    // ---- fp64 refinement when the rank-32/33 boundary is tight ----
    if (selval[K_TOP - 1] - selval[K_TOP] < DELTA) {
        for (int k = t; k < D_IN; k += TB) xrow[k] = x[(size_t)row * D_IN + k] - b_dec[k];
        __syncthreads();
        if (t < C_SEL) {
            const int c = selidx[t];
            double acc = (double)b_enc[c];
            for (int k = 0; k < D_IN; ++k)
                acc = fma((double)xrow[k], (double)W_enc[(size_t)k * D_SAE + c], acc);
            cand[t] = acc > 0.0 ? acc : 0.0;
        }
        __syncthreads();
        if (t == 0) {
            bool  used[C_SEL];
            float nv[K_TOP]; int ni[K_TOP];
            for (int j = 0; j < C_SEL; ++j) used[j] = false;
            for (int s = 0; s < K_TOP; ++s) {
                int bj = -1; double bvv = 0.0; int bidx = 0;
                for (int j = 0; j < C_SEL; ++j) {
                    if (used[j]) continue;
                    const double v = cand[j]; const int idx = selidx[j];
                    if (bj < 0 || v > bvv || (v == bvv && idx < bidx)) { bj = j; bvv = v; bidx = idx; }
                }
                used[bj] = true; nv[s] = (float)bvv; ni[s] = bidx;
            }
            for (int s = 0; s < K_TOP; ++s) { selval[s] = nv[s]; selidx[s] = ni[s]; }
        }
        __syncthreads();
    }

    // ---- write sparse row ----
#pragma unroll
    for (int i = 0; i < QPT; ++i) {
        const int q = t + i * TB;
        const float4 v = *(const float4*)(&zrow[q * 4]);
        float4 o = make_float4(0.f, 0.f, 0.f, 0.f);
        const int base = q * 4;
        if (v.x == NEG_INF) { for (int s = 0; s < K_TOP; ++s) if (selidx[s] == base + 0) { o.x = selval[s]; break; } }
        if (v.y == NEG_INF) { for (int s = 0; s < K_TOP; ++s) if (selidx[s] == base + 1) { o.y = selval[s]; break; } }
        if (v.z == NEG_INF) { for (int s = 0; s < K_TOP; ++s) if (selidx[s] == base + 2) { o.z = selval[s]; break; } }
        if (v.w == NEG_INF) { for (int s = 0; s < K_TOP; ++s) if (selidx[s] == base + 3) { o.w = selval[s]; break; } }
        *(float4*)(&zr[q * 4]) = o;
    }

    // ---- decode ----
    float a0 = b_dec[t], a1 = b_dec[t + 256], a2 = b_dec[t + 512];
#pragma unroll 8
    for (int s = 0; s < K_TOP; ++s) {
        const float v = selval[s];
        const float* wd = W_dec + (size_t)selidx[s] * D_IN;
        a0 = fmaf(v, wd[t],       a0);
        a1 = fmaf(v, wd[t + 256], a1);
        a2 = fmaf(v, wd[t + 512], a2);
    }
    float* xr = x_rec + (size_t)row * D_IN;
    xr[t] = a0; xr[t + 256] = a1; xr[t + 512] = a2;
}

extern "C" void kernel_launch(void* const* d_in, const int* in_sizes, int n_in,
                              void* d_out, int out_size, void* d_ws, size_t ws_size,
                              hipStream_t stream)
{
    const float* x     = (const float*)d_in[0];
    const float* W_enc = (const float*)d_in[1];
    const float* b_enc = (const float*)d_in[2];
    const float* W_dec = (const float*)d_in[3];
    const float* b_dec = (const float*)d_in[4];

    float* out   = (float*)d_out;
    float* x_rec = out;
    float* z     = out + (size_t)N_ROWS * D_IN;

    dim3 g1(D_SAE / BN, N_ROWS / BM);
    sae_encode_gemm<<<g1, 256, 0, stream>>>(x, W_enc, b_enc, b_dec, z);
    sae_topk_decode<<<N_ROWS, TB, 0, stream>>>(z, x, W_enc, b_enc, W_dec, b_dec, x_rec);
}

// Round 3
// 5339.569 us; speedup vs baseline: 1.5324x; 1.5324x over previous
//
#include <hip/hip_runtime.h>

#define N_ROWS 8192
#define D_IN   768
#define D_SAE  24576
#define K_TOP  32
#define C_SEL  40
#define DELTA  1e-4f

// ---------------- GEMM: z = relu((x - b_dec) @ W_enc + b_enc) ----------------
#define BM 128
#define BN 128
#define BK 16
#define LDSS (BM + 4)

__global__ __launch_bounds__(256)
void sae_encode_gemm(const float* __restrict__ x,
                     const float* __restrict__ W_enc,
                     const float* __restrict__ b_enc,
                     const float* __restrict__ b_dec,
                     float* __restrict__ z)
{
    __shared__ float As[BK][LDSS];
    __shared__ float Bs[BK][LDSS];

    const int tid  = threadIdx.x;
    const int bn   = blockIdx.x;
    const int bm   = blockIdx.y;
    const int row0 = bm * BM;
    const int col0 = bn * BN;

    const int tm = tid >> 4;
    const int tn = tid & 15;

    const int lm = tid >> 2;
    const int kq = tid & 3;
    const int lk = tid >> 5;
    const int nq = tid & 31;

    float acc[8][8];
#pragma unroll
    for (int i = 0; i < 8; ++i)
#pragma unroll
        for (int j = 0; j < 8; ++j) acc[i][j] = 0.f;

    for (int k0 = 0; k0 < D_IN; k0 += BK) {
#pragma unroll
        for (int h = 0; h < 2; ++h) {
            const int m = lm + h * 64;
            const float4 xa = *(const float4*)(&x[(size_t)(row0 + m) * D_IN + k0 + kq * 4]);
            const float4 bd = *(const float4*)(&b_dec[k0 + kq * 4]);
            As[kq * 4 + 0][m] = xa.x - bd.x;
            As[kq * 4 + 1][m] = xa.y - bd.y;
            As[kq * 4 + 2][m] = xa.z - bd.z;
            As[kq * 4 + 3][m] = xa.w - bd.w;
        }
#pragma unroll
        for (int h = 0; h < 2; ++h) {
            const int kk = lk + h * 8;
            const float4 wb = *(const float4*)(&W_enc[(size_t)(k0 + kk) * D_SAE + col0 + nq * 4]);
            *(float4*)(&Bs[kk][nq * 4]) = wb;
        }
        __syncthreads();

#pragma unroll
        for (int kk = 0; kk < BK; ++kk) {
            float a[8], b[8];
            *(float4*)(&a[0]) = *(const float4*)(&As[kk][tm * 4]);
            *(float4*)(&a[4]) = *(const float4*)(&As[kk][tm * 4 + 64]);
            *(float4*)(&b[0]) = *(const float4*)(&Bs[kk][tn * 4]);
            *(float4*)(&b[4]) = *(const float4*)(&Bs[kk][tn * 4 + 64]);
#pragma unroll
            for (int i = 0; i < 8; ++i)
#pragma unroll
                for (int j = 0; j < 8; ++j)
                    acc[i][j] = fmaf(a[i], b[j], acc[i][j]);
        }
        __syncthreads();
    }

    const float4 be0 = *(const float4*)(&b_enc[col0 + tn * 4]);
    const float4 be1 = *(const float4*)(&b_enc[col0 + 64 + tn * 4]);
#pragma unroll
    for (int i = 0; i < 8; ++i) {
        const int r = row0 + tm * 4 + (i & 3) + ((i >> 2) * 64);
        float4 v0, v1;
        v0.x = fmaxf(acc[i][0] + be0.x, 0.f);
        v0.y = fmaxf(acc[i][1] + be0.y, 0.f);
        v0.z = fmaxf(acc[i][2] + be0.z, 0.f);
        v0.w = fmaxf(acc[i][3] + be0.w, 0.f);
        v1.x = fmaxf(acc[i][4] + be1.x, 0.f);
        v1.y = fmaxf(acc[i][5] + be1.y, 0.f);
        v1.z = fmaxf(acc[i][6] + be1.z, 0.f);
        v1.w = fmaxf(acc[i][7] + be1.w, 0.f);
        const size_t off = (size_t)r * D_SAE + col0;
        *(float4*)(&z[off + tn * 4])      = v0;
        *(float4*)(&z[off + 64 + tn * 4]) = v1;
    }
}

// ------------- per-row: radix-select top-40, fp64 refine if tight, sparsify, decode -------------
#define TB     256
#define QPT    (D_SAE / 4 / TB)   // 24 float4 per thread
#define HB     2048
#define BNDCAP 224
#define POOLN  512
#define NEGF   -1e30f

__global__ __launch_bounds__(TB)
void sae_topk_decode(float* __restrict__ z,
                     const float* __restrict__ x,
                     const float* __restrict__ W_enc,
                     const float* __restrict__ b_enc,
                     const float* __restrict__ W_dec,
                     const float* __restrict__ b_dec,
                     float* __restrict__ x_rec)
{
    __shared__ int    hist[4 * HB];     // 32 KB, wave-private copies
    __shared__ int    sufx[TB];
    __shared__ float  poolv[POOLN];
    __shared__ int    pooli[POOLN];
    __shared__ float  selv[C_SEL];
    __shared__ int    seli[C_SEL];
    __shared__ float  xrow[D_IN];
    __shared__ double cand[C_SEL];
    __shared__ float  wv4[4];
    __shared__ int    wi4[4], ws4[4];
    __shared__ int    shB, shChi, shB2;
    __shared__ int    nDef, nBnd, scnt;

    const int row = blockIdx.x;
    const int t   = threadIdx.x;
    const int w   = t >> 6;
    const int l   = t & 63;
    float* zr = z + (size_t)row * D_SAE;

    // ---- phase 1: wave-private histograms of top-11 float bits (z >= 0) ----
    for (int i = t; i < 4 * HB; i += TB) hist[i] = 0;
    if (t == 0) { nDef = 0; nBnd = 0; }
    __syncthreads();
    {
        int* hw = &hist[w * HB];
        int zc = 0;
        for (int i = 0; i < QPT; ++i) {
            const float4 v = *(const float4*)(&zr[(size_t)(t + i * TB) * 4]);
#define H1(f) { if (f > 0.f) atomicAdd(&hw[__float_as_uint(f) >> 20], 1); else ++zc; }
            H1(v.x) H1(v.y) H1(v.z) H1(v.w)
#undef H1
        }
        if (zc) atomicAdd(&hw[0], zc);
    }
    __syncthreads();
    // merge 4 copies; thread t owns buckets [8t, 8t+8)
    int cnt8[8]; int tot = 0;
#pragma unroll
    for (int j = 0; j < 8; ++j) {
        const int b = t * 8 + j;
        const int c = hist[b] + hist[HB + b] + hist[2 * HB + b] + hist[3 * HB + b];
        cnt8[j] = c; tot += c;
    }
    sufx[t] = tot;
    __syncthreads();
    // inclusive suffix scan over thread totals
    for (int off = 1; off < TB; off <<= 1) {
        const int a = sufx[t];
        const int b = (t + off < TB) ? sufx[t + off] : 0;
        __syncthreads();
        sufx[t] = a + b;
        __syncthreads();
    }
    {
        int run = (t + 1 < TB) ? sufx[t + 1] : 0;   // strictly above my bucket range
#pragma unroll
        for (int j = 7; j >= 0; --j) {
            const int c = cnt8[j];
            if (run < C_SEL && run + c >= C_SEL) { shB = t * 8 + j; shChi = run; }
            run += c;
        }
    }
    __syncthreads();
    const int B = shB;

    // ---- phase 2: collect definite (> B) and boundary (== B) ----
    for (int i = 0; i < QPT; ++i) {
        const float4 v = *(const float4*)(&zr[(size_t)(t + i * TB) * 4]);
        const int base = (t + i * TB) * 4;
#define H2(f, o) { const unsigned bb = __float_as_uint(f); const int tb_ = (int)(bb >> 20); \
        if (tb_ > B) { const int p = atomicAdd(&nDef, 1); poolv[p] = f; pooli[p] = base + o; } \
        else if (tb_ == B) { const int p = atomicAdd(&nBnd, 1); if (p < BNDCAP) { poolv[C_SEL + p] = f; pooli[C_SEL + p] = base + o; } } }
        H2(v.x, 0) H2(v.y, 1) H2(v.z, 2) H2(v.w, 3)
#undef H2
    }
    __syncthreads();

    // ---- level-2 refinement if boundary bucket overflows (ties) ----
    if (nBnd > BNDCAP) {
        const int chi = shChi;
        for (int i = t; i < HB; i += TB) hist[i] = 0;
        __syncthreads();
        for (int i = 0; i < QPT; ++i) {
            const float4 v = *(const float4*)(&zr[(size_t)(t + i * TB) * 4]);
#define S1(f) { const unsigned bb = __float_as_uint(f); if ((int)(bb >> 20) == B) atomicAdd(&hist[(bb >> 9) & 0x7FF], 1); }
            S1(v.x) S1(v.y) S1(v.z) S1(v.w)
#undef S1
        }
        __syncthreads();
        const int need0 = C_SEL - chi;
        int c8[8]; int tt = 0;
#pragma unroll
        for (int j = 0; j < 8; ++j) { const int c = hist[t * 8 + j]; c8[j] = c; tt += c; }
        __syncthreads();
        sufx[t] = tt;
        __syncthreads();
        for (int off = 1; off < TB; off <<= 1) {
            const int a = sufx[t];
            const int b = (t + off < TB) ? sufx[t + off] : 0;
            __syncthreads();
            sufx[t] = a + b;
            __syncthreads();
        }
        {
            int run = (t + 1 < TB) ? sufx[t + 1] : 0;
#pragma unroll
            for (int j = 7; j >= 0; --j) {
                const int c = c8[j];
                if (run < need0 && run + c >= need0) shB2 = t * 8 + j;
                run += c;
            }
        }
        if (t == 0) nBnd = 0;
        __syncthreads();
        const int B2 = shB2;
        for (int i = 0; i < QPT; ++i) {
            const float4 v = *(const float4*)(&zr[(size_t)(t + i * TB) * 4]);
            const int base = (t + i * TB) * 4;
#define S2(f, o) { const unsigned bb = __float_as_uint(f); if ((int)(bb >> 20) == B) { const int sb = (int)((bb >> 9) & 0x7FF); \
            if (sb > B2) { const int p = atomicAdd(&nDef, 1); poolv[p] = f; pooli[p] = base + o; } \
            else if (sb == B2) { const int p = atomicAdd(&nBnd, 1); if (p < BNDCAP) { poolv[C_SEL + p] = f; pooli[C_SEL + p] = base + o; } } } }
            S2(v.x, 0) S2(v.y, 1) S2(v.z, 2) S2(v.w, 3)
#undef S2
        }
        __syncthreads();
        // ---- last resort: fill by lowest index among 22-bit ties (refine path re-orders) ----
        if (nBnd > BNDCAP) {
            const int need = C_SEL - nDef;
            int lo = 0, hi = D_SAE - 1;
            while (lo < hi) {
                const int mid = (lo + hi) >> 1;
                if (t == 0) scnt = 0;
                __syncthreads();
                int lc = 0;
                for (int i = 0; i < QPT; ++i) {
                    const float4 v = *(const float4*)(&zr[(size_t)(t + i * TB) * 4]);
                    const int base = (t + i * TB) * 4;
#define S3(f, o) { const unsigned bb = __float_as_uint(f); if ((int)(bb >> 20) == B && (int)((bb >> 9) & 0x7FF) == B2 && (base + o) <= mid) ++lc; }
                    S3(v.x, 0) S3(v.y, 1) S3(v.z, 2) S3(v.w, 3)
#undef S3
                }
                if (lc) atomicAdd(&scnt, lc);
                __syncthreads();
                if (scnt >= need) hi = mid; else lo = mid + 1;
                __syncthreads();
            }
            for (int i = 0; i < QPT; ++i) {
                const float4 v = *(const float4*)(&zr[(size_t)(t + i * TB) * 4]);
                const int base = (t + i * TB) * 4;
#define S4(f, o) { const unsigned bb = __float_as_uint(f); if ((int)(bb >> 20) == B && (int)((bb >> 9) & 0x7FF) == B2 && (base + o) <= lo) { const int p = atomicAdd(&nDef, 1); poolv[p] = f; pooli[p] = base + o; } }
                S4(v.x, 0) S4(v.y, 1) S4(v.z, 2) S4(v.w, 3)
#undef S4
            }
            if (t == 0) nBnd = 0;
            __syncthreads();
        }
    }

    // ---- pad pool and select top-40 by (value desc, index asc) ----
    {
        const int ndef  = nDef;
        const int nbndc = (nBnd < BNDCAP) ? nBnd : BNDCAP;
        for (int i = t; i < POOLN; i += TB)
            if (!(i < ndef) && !(i >= C_SEL && i < C_SEL + nbndc)) { poolv[i] = NEGF; pooli[i] = 1 << 30; }
    }
    __syncthreads();

    for (int s = 0; s < C_SEL; ++s) {
        float v1 = poolv[t]; int j1 = pooli[t]; int s1 = t;
        {
            const float v2 = poolv[t + TB]; const int j2 = pooli[t + TB];
            if (v2 > v1 || (v2 == v1 && j2 < j1)) { v1 = v2; j1 = j2; s1 = t + TB; }
        }
#pragma unroll
        for (int off = 32; off > 0; off >>= 1) {
            const float ov = __shfl_xor(v1, off);
            const int   oj = __shfl_xor(j1, off);
            const int   os = __shfl_xor(s1, off);
            if (ov > v1 || (ov == v1 && oj < j1)) { v1 = ov; j1 = oj; s1 = os; }
        }
        if (l == 0) { wv4[w] = v1; wi4[w] = j1; ws4[w] = s1; }
        __syncthreads();
        if (t == 0) {
            float gv = wv4[0]; int gj = wi4[0]; int gs = ws4[0];
#pragma unroll
            for (int q = 1; q < 4; ++q)
                if (wv4[q] > gv || (wv4[q] == gv && wi4[q] < gj)) { gv = wv4[q]; gj = wi4[q]; gs = ws4[q]; }
            selv[s] = gv; seli[s] = gj;
            poolv[gs] = NEGF; pooli[gs] = 1 << 30;
        }
        __syncthreads();
    }

    // ---- fp64 refine when rank-32/33 boundary is tight (wave-parallel) ----
    if (selv[K_TOP - 1] - selv[K_TOP] < DELTA) {
        for (int k = t; k < D_IN; k += TB) xrow[k] = x[(size_t)row * D_IN + k] - b_dec[k];
        __syncthreads();
        for (int j = w; j < C_SEL; j += 4) {
            const int c = seli[j];
            double acc = 0.0;
#pragma unroll
            for (int q = 0; q < D_IN / 64; ++q) {
                const int k = l + q * 64;
                acc = fma((double)xrow[k], (double)W_enc[(size_t)k * D_SAE + c], acc);
            }
#pragma unroll
            for (int off = 32; off > 0; off >>= 1) acc += __shfl_down(acc, off);
            if (l == 0) {
                const double vv = acc + (double)b_enc[c];
                cand[j] = vv > 0.0 ? vv : 0.0;
            }
        }
        __syncthreads();
        if (t == 0) {
            bool used[C_SEL]; float nv[K_TOP]; int ni[K_TOP];
            for (int j = 0; j < C_SEL; ++j) used[j] = false;
            for (int s = 0; s < K_TOP; ++s) {
                int bj = -1; double bvv = 0.0; int bidx = 0;
                for (int j = 0; j < C_SEL; ++j) {
                    if (used[j]) continue;
                    const double v = cand[j]; const int idx = seli[j];
                    if (bj < 0 || v > bvv || (v == bvv && idx < bidx)) { bj = j; bvv = v; bidx = idx; }
                }
                used[bj] = true; nv[s] = (float)bvv; ni[s] = bidx;
            }
            for (int s = 0; s < K_TOP; ++s) { selv[s] = nv[s]; seli[s] = ni[s]; }
        }
        __syncthreads();
    }

    // ---- write sparse row: zeros + scatter 32 ----
    {
        const float4 z4 = make_float4(0.f, 0.f, 0.f, 0.f);
        for (int i = 0; i < QPT; ++i)
            *(float4*)(&zr[(size_t)(t + i * TB) * 4]) = z4;
    }
    __syncthreads();
    if (t < K_TOP) zr[seli[t]] = selv[t];

    // ---- decode: x_rec[row] = b_dec + sum_s selv[s] * W_dec[seli[s], :] ----
    float a0 = b_dec[t], a1 = b_dec[t + 256], a2 = b_dec[t + 512];
#pragma unroll 8
    for (int s = 0; s < K_TOP; ++s) {
        const float v = selv[s];
        const float* wd = W_dec + (size_t)seli[s] * D_IN;
        a0 = fmaf(v, wd[t],       a0);
        a1 = fmaf(v, wd[t + 256], a1);
        a2 = fmaf(v, wd[t + 512], a2);
    }
    float* xr = x_rec + (size_t)row * D_IN;
    xr[t] = a0; xr[t + 256] = a1; xr[t + 512] = a2;
}

extern "C" void kernel_launch(void* const* d_in, const int* in_sizes, int n_in,
                              void* d_out, int out_size, void* d_ws, size_t ws_size,
                              hipStream_t stream)
{
    const float* x     = (const float*)d_in[0];
    const float* W_enc = (const float*)d_in[1];
    const float* b_enc = (const float*)d_in[2];
    const float* W_dec = (const float*)d_in[3];
    const float* b_dec = (const float*)d_in[4];

    float* out   = (float*)d_out;
    float* x_rec = out;
    float* z     = out + (size_t)N_ROWS * D_IN;

    dim3 g1(D_SAE / BN, N_ROWS / BM);
    sae_encode_gemm<<<g1, 256, 0, stream>>>(x, W_enc, b_enc, b_dec, z);
    sae_topk_decode<<<N_ROWS, TB, 0, stream>>>(z, x, W_enc, b_enc, W_dec, b_dec, x_rec);
}

// Round 4
// 3496.543 us; speedup vs baseline: 2.3401x; 1.5271x over previous
//
#include <hip/hip_runtime.h>

#define N_ROWS 8192
#define D_IN   768
#define D_SAE  24576
#define K_TOP  32
#define C_SEL  40
#define DELTA  2e-4f

typedef __attribute__((ext_vector_type(8))) short bf16x8;
typedef __attribute__((ext_vector_type(4))) float f32x4;

__device__ __forceinline__ ushort f2bf(float f) {
    const unsigned u = __float_as_uint(f);
    return (ushort)((u + 0x7FFFu + ((u >> 16) & 1u)) >> 16);
}
__device__ __forceinline__ float bf2f(ushort h) {
    return __uint_as_float(((unsigned)h) << 16);
}

// ---------------- split-bf16 MFMA GEMM: z = relu((x - b_dec) @ W_enc + b_enc) ----------------
// block tile 128x192, 4 waves (2x2), wave tile 64x96 = 4x6 of 16x16x32 MFMA, BK=32
#define GBM 128
#define GBN 192
#define GBK 32

__global__ __launch_bounds__(256, 2)
void sae_encode_mfma(const float* __restrict__ x,
                     const float* __restrict__ W_enc,
                     const float* __restrict__ b_enc,
                     const float* __restrict__ b_dec,
                     float* __restrict__ z)
{
    // B tile, transposed+split: plane(hi/lo), k-chunk, col, k-in-chunk. 24 KB.
    __shared__ ushort Bs[2][4][GBN][8];

    const int tid  = threadIdx.x;
    const int lane = tid & 63;
    const int wid  = tid >> 6;
    const int wr   = wid >> 1;          // wave row 0..1
    const int wc   = wid & 1;           // wave col 0..1
    const int l15  = lane & 15;
    const int lc   = lane >> 4;         // k-chunk 0..3

    const int col0  = blockIdx.x * GBN;
    const int row_w = blockIdx.y * GBM + wr * 64;

    f32x4 acc[4][6];
#pragma unroll
    for (int i = 0; i < 4; ++i)
#pragma unroll
        for (int j = 0; j < 6; ++j) acc[i][j] = (f32x4){0.f, 0.f, 0.f, 0.f};

    for (int kt = 0; kt < D_IN / GBK; ++kt) {
        const int k0 = kt * GBK;

        // ---- B staging loads (global, no LDS dependency): wave `wid` owns k-chunk wid ----
        float bvv[3][8];
#pragma unroll
        for (int np = 0; np < 3; ++np)
#pragma unroll
            for (int it = 0; it < 8; ++it)
                bvv[np][it] = W_enc[(size_t)(k0 + wid * 8 + it) * D_SAE + col0 + np * 64 + lane];

        // ---- A fragments direct from global (x is [M][K], 8 consecutive k per lane) ----
        const float4 bd0 = *(const float4*)(&b_dec[k0 + lc * 8]);
        const float4 bd1 = *(const float4*)(&b_dec[k0 + lc * 8 + 4]);
        bf16x8 ah[4], al[4];
#pragma unroll
        for (int rt = 0; rt < 4; ++rt) {
            const size_t off = (size_t)(row_w + rt * 16 + l15) * D_IN + k0 + lc * 8;
            const float4 a0 = *(const float4*)(&x[off]);
            const float4 a1 = *(const float4*)(&x[off + 4]);
            float e[8];
            e[0] = a0.x - bd0.x; e[1] = a0.y - bd0.y; e[2] = a0.z - bd0.z; e[3] = a0.w - bd0.w;
            e[4] = a1.x - bd1.x; e[5] = a1.y - bd1.y; e[6] = a1.z - bd1.z; e[7] = a1.w - bd1.w;
#pragma unroll
            for (int j = 0; j < 8; ++j) {
                const ushort h = f2bf(e[j]);
                ah[rt][j] = (short)h;
                al[rt][j] = (short)f2bf(e[j] - bf2f(h));
            }
        }

        // ---- convert B to hi/lo packed ----
        uint4 bh_pk[3], bl_pk[3];
#pragma unroll
        for (int np = 0; np < 3; ++np) {
            ushort h[8], l[8];
#pragma unroll
            for (int it = 0; it < 8; ++it) {
                h[it] = f2bf(bvv[np][it]);
                l[it] = f2bf(bvv[np][it] - bf2f(h[it]));
            }
            bh_pk[np] = make_uint4((unsigned)h[0] | ((unsigned)h[1] << 16),
                                   (unsigned)h[2] | ((unsigned)h[3] << 16),
                                   (unsigned)h[4] | ((unsigned)h[5] << 16),
                                   (unsigned)h[6] | ((unsigned)h[7] << 16));
            bl_pk[np] = make_uint4((unsigned)l[0] | ((unsigned)l[1] << 16),
                                   (unsigned)l[2] | ((unsigned)l[3] << 16),
                                   (unsigned)l[4] | ((unsigned)l[5] << 16),
                                   (unsigned)l[6] | ((unsigned)l[7] << 16));
        }

        __syncthreads();   // previous iteration's fragment reads complete
#pragma unroll
        for (int np = 0; np < 3; ++np) {
            const int n = np * 64 + lane;
            *(uint4*)(&Bs[0][wid][n][0]) = bh_pk[np];
            *(uint4*)(&Bs[1][wid][n][0]) = bl_pk[np];
        }
        __syncthreads();   // B tile visible

        // ---- MFMA: 6 col-tiles x 4 row-tiles x 3 terms ----
#pragma unroll
        for (int ct = 0; ct < 6; ++ct) {
            const int n = wc * 96 + ct * 16 + l15;
            const bf16x8 bh = *(const bf16x8*)(&Bs[0][lc][n][0]);
            const bf16x8 bl = *(const bf16x8*)(&Bs[1][lc][n][0]);
#pragma unroll
            for (int rt = 0; rt < 4; ++rt) {
                acc[rt][ct] = __builtin_amdgcn_mfma_f32_16x16x32_bf16(ah[rt], bh, acc[rt][ct], 0, 0, 0);
                acc[rt][ct] = __builtin_amdgcn_mfma_f32_16x16x32_bf16(ah[rt], bl, acc[rt][ct], 0, 0, 0);
                acc[rt][ct] = __builtin_amdgcn_mfma_f32_16x16x32_bf16(al[rt], bh, acc[rt][ct], 0, 0, 0);
            }
        }
    }

    // ---- epilogue: + b_enc, relu, store. C/D: col=lane&15, row=(lane>>4)*4+reg ----
#pragma unroll
    for (int ct = 0; ct < 6; ++ct) {
        const int col = col0 + wc * 96 + ct * 16 + l15;
        const float bec = b_enc[col];
#pragma unroll
        for (int rt = 0; rt < 4; ++rt) {
            const int rowb = row_w + rt * 16 + lc * 4;
#pragma unroll
            for (int r = 0; r < 4; ++r)
                z[(size_t)(rowb + r) * D_SAE + col] = fmaxf(acc[rt][ct][r] + bec, 0.f);
        }
    }
}

// ------------- per-row: radix-select top-40, fp64 refine if tight, sparsify, decode -------------
#define TB     256
#define QPT    (D_SAE / 4 / TB)   // 24 float4 per thread
#define HB     2048
#define BNDCAP 224
#define POOLN  512
#define NEGF   -1e30f

__global__ __launch_bounds__(TB)
void sae_topk_decode(float* __restrict__ z,
                     const float* __restrict__ x,
                     const float* __restrict__ W_enc,
                     const float* __restrict__ b_enc,
                     const float* __restrict__ W_dec,
                     const float* __restrict__ b_dec,
                     float* __restrict__ x_rec)
{
    __shared__ int    hist[4 * HB];     // 32 KB, wave-private copies
    __shared__ int    sufx[TB];
    __shared__ float  poolv[POOLN];
    __shared__ int    pooli[POOLN];
    __shared__ float  selv[C_SEL];
    __shared__ int    seli[C_SEL];
    __shared__ float  xrow[D_IN];
    __shared__ double cand[C_SEL];
    __shared__ float  wv4[4];
    __shared__ int    wi4[4], ws4[4];
    __shared__ int    shB, shChi, shB2;
    __shared__ int    nDef, nBnd, scnt;

    const int row = blockIdx.x;
    const int t   = threadIdx.x;
    const int w   = t >> 6;
    const int l   = t & 63;
    float* zr = z + (size_t)row * D_SAE;

    // ---- phase 1: wave-private histograms of top-11 float bits (z >= 0) ----
    for (int i = t; i < 4 * HB; i += TB) hist[i] = 0;
    if (t == 0) { nDef = 0; nBnd = 0; }
    __syncthreads();
    {
        int* hw = &hist[w * HB];
        int zc = 0;
        for (int i = 0; i < QPT; ++i) {
            const float4 v = *(const float4*)(&zr[(size_t)(t + i * TB) * 4]);
#define H1(f) { if (f > 0.f) atomicAdd(&hw[__float_as_uint(f) >> 20], 1); else ++zc; }
            H1(v.x) H1(v.y) H1(v.z) H1(v.w)
#undef H1
        }
        if (zc) atomicAdd(&hw[0], zc);
    }
    __syncthreads();
    // merge 4 copies; thread t owns buckets [8t, 8t+8)
    int cnt8[8]; int tot = 0;
#pragma unroll
    for (int j = 0; j < 8; ++j) {
        const int b = t * 8 + j;
        const int c = hist[b] + hist[HB + b] + hist[2 * HB + b] + hist[3 * HB + b];
        cnt8[j] = c; tot += c;
    }
    sufx[t] = tot;
    __syncthreads();
    // inclusive suffix scan over thread totals
    for (int off = 1; off < TB; off <<= 1) {
        const int a = sufx[t];
        const int b = (t + off < TB) ? sufx[t + off] : 0;
        __syncthreads();
        sufx[t] = a + b;
        __syncthreads();
    }
    {
        int run = (t + 1 < TB) ? sufx[t + 1] : 0;   // strictly above my bucket range
#pragma unroll
        for (int j = 7; j >= 0; --j) {
            const int c = cnt8[j];
            if (run < C_SEL && run + c >= C_SEL) { shB = t * 8 + j; shChi = run; }
            run += c;
        }
    }
    __syncthreads();
    const int B = shB;

    // ---- phase 2: collect definite (> B) and boundary (== B) ----
    for (int i = 0; i < QPT; ++i) {
        const float4 v = *(const float4*)(&zr[(size_t)(t + i * TB) * 4]);
        const int base = (t + i * TB) * 4;
#define H2(f, o) { const unsigned bb = __float_as_uint(f); const int tb_ = (int)(bb >> 20); \
        if (tb_ > B) { const int p = atomicAdd(&nDef, 1); poolv[p] = f; pooli[p] = base + o; } \
        else if (tb_ == B) { const int p = atomicAdd(&nBnd, 1); if (p < BNDCAP) { poolv[C_SEL + p] = f; pooli[C_SEL + p] = base + o; } } }
        H2(v.x, 0) H2(v.y, 1) H2(v.z, 2) H2(v.w, 3)
#undef H2
    }
    __syncthreads();

    // ---- level-2 refinement if boundary bucket overflows (ties) ----
    if (nBnd > BNDCAP) {
        const int chi = shChi;
        for (int i = t; i < HB; i += TB) hist[i] = 0;
        __syncthreads();
        for (int i = 0; i < QPT; ++i) {
            const float4 v = *(const float4*)(&zr[(size_t)(t + i * TB) * 4]);
#define S1(f) { const unsigned bb = __float_as_uint(f); if ((int)(bb >> 20) == B) atomicAdd(&hist[(bb >> 9) & 0x7FF], 1); }
            S1(v.x) S1(v.y) S1(v.z) S1(v.w)
#undef S1
        }
        __syncthreads();
        const int need0 = C_SEL - chi;
        int c8[8]; int tt = 0;
#pragma unroll
        for (int j = 0; j < 8; ++j) { const int c = hist[t * 8 + j]; c8[j] = c; tt += c; }
        __syncthreads();
        sufx[t] = tt;
        __syncthreads();
        for (int off = 1; off < TB; off <<= 1) {
            const int a = sufx[t];
            const int b = (t + off < TB) ? sufx[t + off] : 0;
            __syncthreads();
            sufx[t] = a + b;
            __syncthreads();
        }
        {
            int run = (t + 1 < TB) ? sufx[t + 1] : 0;
#pragma unroll
            for (int j = 7; j >= 0; --j) {
                const int c = c8[j];
                if (run < need0 && run + c >= need0) shB2 = t * 8 + j;
                run += c;
            }
        }
        if (t == 0) nBnd = 0;
        __syncthreads();
        const int B2 = shB2;
        for (int i = 0; i < QPT; ++i) {
            const float4 v = *(const float4*)(&zr[(size_t)(t + i * TB) * 4]);
            const int base = (t + i * TB) * 4;
#define S2(f, o) { const unsigned bb = __float_as_uint(f); if ((int)(bb >> 20) == B) { const int sb = (int)((bb >> 9) & 0x7FF); \
            if (sb > B2) { const int p = atomicAdd(&nDef, 1); poolv[p] = f; pooli[p] = base + o; } \
            else if (sb == B2) { const int p = atomicAdd(&nBnd, 1); if (p < BNDCAP) { poolv[C_SEL + p] = f; pooli[C_SEL + p] = base + o; } } } }
            S2(v.x, 0) S2(v.y, 1) S2(v.z, 2) S2(v.w, 3)
#undef S2
        }
        __syncthreads();
        // ---- last resort: fill by lowest index among 22-bit ties (refine path re-orders) ----
        if (nBnd > BNDCAP) {
            const int need = C_SEL - nDef;
            int lo = 0, hi = D_SAE - 1;
            while (lo < hi) {
                const int mid = (lo + hi) >> 1;
                if (t == 0) scnt = 0;
                __syncthreads();
                int lc2 = 0;
                for (int i = 0; i < QPT; ++i) {
                    const float4 v = *(const float4*)(&zr[(size_t)(t + i * TB) * 4]);
                    const int base = (t + i * TB) * 4;
#define S3(f, o) { const unsigned bb = __float_as_uint(f); if ((int)(bb >> 20) == B && (int)((bb >> 9) & 0x7FF) == B2 && (base + o) <= mid) ++lc2; }
                    S3(v.x, 0) S3(v.y, 1) S3(v.z, 2) S3(v.w, 3)
#undef S3
                }
                if (lc2) atomicAdd(&scnt, lc2);
                __syncthreads();
                if (scnt >= need) hi = mid; else lo = mid + 1;
                __syncthreads();
            }
            for (int i = 0; i < QPT; ++i) {
                const float4 v = *(const float4*)(&zr[(size_t)(t + i * TB) * 4]);
                const int base = (t + i * TB) * 4;
#define S4(f, o) { const unsigned bb = __float_as_uint(f); if ((int)(bb >> 20) == B && (int)((bb >> 9) & 0x7FF) == B2 && (base + o) <= lo) { const int p = atomicAdd(&nDef, 1); poolv[p] = f; pooli[p] = base + o; } }
                S4(v.x, 0) S4(v.y, 1) S4(v.z, 2) S4(v.w, 3)
#undef S4
            }
            if (t == 0) nBnd = 0;
            __syncthreads();
        }
    }

    // ---- pad pool and select top-40 by (value desc, index asc) ----
    {
        const int ndef  = nDef;
        const int nbndc = (nBnd < BNDCAP) ? nBnd : BNDCAP;
        for (int i = t; i < POOLN; i += TB)
            if (!(i < ndef) && !(i >= C_SEL && i < C_SEL + nbndc)) { poolv[i] = NEGF; pooli[i] = 1 << 30; }
    }
    __syncthreads();

    for (int s = 0; s < C_SEL; ++s) {
        float v1 = poolv[t]; int j1 = pooli[t]; int s1 = t;
        {
            const float v2 = poolv[t + TB]; const int j2 = pooli[t + TB];
            if (v2 > v1 || (v2 == v1 && j2 < j1)) { v1 = v2; j1 = j2; s1 = t + TB; }
        }
#pragma unroll
        for (int off = 32; off > 0; off >>= 1) {
            const float ov = __shfl_xor(v1, off);
            const int   oj = __shfl_xor(j1, off);
            const int   os = __shfl_xor(s1, off);
            if (ov > v1 || (ov == v1 && oj < j1)) { v1 = ov; j1 = oj; s1 = os; }
        }
        if (l == 0) { wv4[w] = v1; wi4[w] = j1; ws4[w] = s1; }
        __syncthreads();
        if (t == 0) {
            float gv = wv4[0]; int gj = wi4[0]; int gs = ws4[0];
#pragma unroll
            for (int q = 1; q < 4; ++q)
                if (wv4[q] > gv || (wv4[q] == gv && wi4[q] < gj)) { gv = wv4[q]; gj = wi4[q]; gs = ws4[q]; }
            selv[s] = gv; seli[s] = gj;
            poolv[gs] = NEGF; pooli[gs] = 1 << 30;
        }
        __syncthreads();
    }

    // ---- fp64 refine when rank-32/33 boundary is tight (wave-parallel) ----
    if (selv[K_TOP - 1] - selv[K_TOP] < DELTA) {
        for (int k = t; k < D_IN; k += TB) xrow[k] = x[(size_t)row * D_IN + k] - b_dec[k];
        __syncthreads();
        for (int j = w; j < C_SEL; j += 4) {
            const int c = seli[j];
            double acc = 0.0;
#pragma unroll
            for (int q = 0; q < D_IN / 64; ++q) {
                const int k = l + q * 64;
                acc = fma((double)xrow[k], (double)W_enc[(size_t)k * D_SAE + c], acc);
            }
#pragma unroll
            for (int off = 32; off > 0; off >>= 1) acc += __shfl_down(acc, off);
            if (l == 0) {
                const double vv = acc + (double)b_enc[c];
                cand[j] = vv > 0.0 ? vv : 0.0;
            }
        }
        __syncthreads();
        if (t == 0) {
            bool used[C_SEL]; float nv[K_TOP]; int ni[K_TOP];
            for (int j = 0; j < C_SEL; ++j) used[j] = false;
            for (int s = 0; s < K_TOP; ++s) {
                int bj = -1; double bvv = 0.0; int bidx = 0;
                for (int j = 0; j < C_SEL; ++j) {
                    if (used[j]) continue;
                    const double v = cand[j]; const int idx = seli[j];
                    if (bj < 0 || v > bvv || (v == bvv && idx < bidx)) { bj = j; bvv = v; bidx = idx; }
                }
                used[bj] = true; nv[s] = (float)bvv; ni[s] = bidx;
            }
            for (int s = 0; s < K_TOP; ++s) { selv[s] = nv[s]; seli[s] = ni[s]; }
        }
        __syncthreads();
    }

    // ---- write sparse row: zeros + scatter 32 ----
    {
        const float4 z4 = make_float4(0.f, 0.f, 0.f, 0.f);
        for (int i = 0; i < QPT; ++i)
            *(float4*)(&zr[(size_t)(t + i * TB) * 4]) = z4;
    }
    __syncthreads();
    if (t < K_TOP) zr[seli[t]] = selv[t];

    // ---- decode: x_rec[row] = b_dec + sum_s selv[s] * W_dec[seli[s], :] ----
    float a0 = b_dec[t], a1 = b_dec[t + 256], a2 = b_dec[t + 512];
#pragma unroll 8
    for (int s = 0; s < K_TOP; ++s) {
        const float v = selv[s];
        const float* wd = W_dec + (size_t)seli[s] * D_IN;
        a0 = fmaf(v, wd[t],       a0);
        a1 = fmaf(v, wd[t + 256], a1);
        a2 = fmaf(v, wd[t + 512], a2);
    }
    float* xr = x_rec + (size_t)row * D_IN;
    xr[t] = a0; xr[t + 256] = a1; xr[t + 512] = a2;
}

extern "C" void kernel_launch(void* const* d_in, const int* in_sizes, int n_in,
                              void* d_out, int out_size, void* d_ws, size_t ws_size,
                              hipStream_t stream)
{
    const float* x     = (const float*)d_in[0];
    const float* W_enc = (const float*)d_in[1];
    const float* b_enc = (const float*)d_in[2];
    const float* W_dec = (const float*)d_in[3];
    const float* b_dec = (const float*)d_in[4];

    float* out   = (float*)d_out;
    float* x_rec = out;
    float* z     = out + (size_t)N_ROWS * D_IN;

    dim3 g1(D_SAE / GBN, N_ROWS / GBM);    // 128 x 64
    sae_encode_mfma<<<g1, 256, 0, stream>>>(x, W_enc, b_enc, b_dec, z);
    sae_topk_decode<<<N_ROWS, TB, 0, stream>>>(z, x, W_enc, b_enc, W_dec, b_dec, x_rec);
}

// Round 6
// 2182.246 us; speedup vs baseline: 3.7495x; 1.6023x over previous
//
#include <hip/hip_runtime.h>

#define N_ROWS 8192
#define D_IN   768
#define D_SAE  24576
#define K_TOP  32
#define C_SEL  40
#define DELTA  2e-4f

typedef __attribute__((ext_vector_type(8))) short bf16x8;
typedef __attribute__((ext_vector_type(4))) float f32x4;

__device__ __forceinline__ ushort f2bf(float f) {
    const unsigned u = __float_as_uint(f);
    return (ushort)((u + 0x7FFFu + ((u >> 16) & 1u)) >> 16);
}
__device__ __forceinline__ float bf2f(ushort h) {
    return __uint_as_float(((unsigned)h) << 16);
}

// ---------------- split-bf16 MFMA GEMM: z = relu((x - b_dec) @ W_enc + b_enc) ----------------
#define GBM 128
#define GBN 192
#define GBK 32

__global__ __launch_bounds__(256, 2)
void sae_encode_mfma(const float* __restrict__ x,
                     const float* __restrict__ W_enc,
                     const float* __restrict__ b_enc,
                     const float* __restrict__ b_dec,
                     float* __restrict__ z)
{
    __shared__ ushort Bs[2][4][GBN][8];

    const int tid  = threadIdx.x;
    const int lane = tid & 63;
    const int wid  = tid >> 6;
    const int wr   = wid >> 1;
    const int wc   = wid & 1;
    const int l15  = lane & 15;
    const int lc   = lane >> 4;

    const int col0  = blockIdx.x * GBN;
    const int row_w = blockIdx.y * GBM + wr * 64;

    f32x4 acc[4][6];
#pragma unroll
    for (int i = 0; i < 4; ++i)
#pragma unroll
        for (int j = 0; j < 6; ++j) acc[i][j] = (f32x4){0.f, 0.f, 0.f, 0.f};

    for (int kt = 0; kt < D_IN / GBK; ++kt) {
        const int k0 = kt * GBK;

        float bvv[3][8];
#pragma unroll
        for (int np = 0; np < 3; ++np)
#pragma unroll
            for (int it = 0; it < 8; ++it)
                bvv[np][it] = W_enc[(size_t)(k0 + wid * 8 + it) * D_SAE + col0 + np * 64 + lane];

        const float4 bd0 = *(const float4*)(&b_dec[k0 + lc * 8]);
        const float4 bd1 = *(const float4*)(&b_dec[k0 + lc * 8 + 4]);
        bf16x8 ah[4], al[4];
#pragma unroll
        for (int rt = 0; rt < 4; ++rt) {
            const size_t off = (size_t)(row_w + rt * 16 + l15) * D_IN + k0 + lc * 8;
            const float4 a0 = *(const float4*)(&x[off]);
            const float4 a1 = *(const float4*)(&x[off + 4]);
            float e[8];
            e[0] = a0.x - bd0.x; e[1] = a0.y - bd0.y; e[2] = a0.z - bd0.z; e[3] = a0.w - bd0.w;
            e[4] = a1.x - bd1.x; e[5] = a1.y - bd1.y; e[6] = a1.z - bd1.z; e[7] = a1.w - bd1.w;
#pragma unroll
            for (int j = 0; j < 8; ++j) {
                const ushort h = f2bf(e[j]);
                ah[rt][j] = (short)h;
                al[rt][j] = (short)f2bf(e[j] - bf2f(h));
            }
        }

        uint4 bh_pk[3], bl_pk[3];
#pragma unroll
        for (int np = 0; np < 3; ++np) {
            ushort h[8], l[8];
#pragma unroll
            for (int it = 0; it < 8; ++it) {
                h[it] = f2bf(bvv[np][it]);
                l[it] = f2bf(bvv[np][it] - bf2f(h[it]));
            }
            bh_pk[np] = make_uint4((unsigned)h[0] | ((unsigned)h[1] << 16),
                                   (unsigned)h[2] | ((unsigned)h[3] << 16),
                                   (unsigned)h[4] | ((unsigned)h[5] << 16),
                                   (unsigned)h[6] | ((unsigned)h[7] << 16));
            bl_pk[np] = make_uint4((unsigned)l[0] | ((unsigned)l[1] << 16),
                                   (unsigned)l[2] | ((unsigned)l[3] << 16),
                                   (unsigned)l[4] | ((unsigned)l[5] << 16),
                                   (unsigned)l[6] | ((unsigned)l[7] << 16));
        }

        __syncthreads();
#pragma unroll
        for (int np = 0; np < 3; ++np) {
            const int n = np * 64 + lane;
            *(uint4*)(&Bs[0][wid][n][0]) = bh_pk[np];
            *(uint4*)(&Bs[1][wid][n][0]) = bl_pk[np];
        }
        __syncthreads();

#pragma unroll
        for (int ct = 0; ct < 6; ++ct) {
            const int n = wc * 96 + ct * 16 + l15;
            const bf16x8 bh = *(const bf16x8*)(&Bs[0][lc][n][0]);
            const bf16x8 bl = *(const bf16x8*)(&Bs[1][lc][n][0]);
#pragma unroll
            for (int rt = 0; rt < 4; ++rt) {
                acc[rt][ct] = __builtin_amdgcn_mfma_f32_16x16x32_bf16(ah[rt], bh, acc[rt][ct], 0, 0, 0);
                acc[rt][ct] = __builtin_amdgcn_mfma_f32_16x16x32_bf16(ah[rt], bl, acc[rt][ct], 0, 0, 0);
                acc[rt][ct] = __builtin_amdgcn_mfma_f32_16x16x32_bf16(al[rt], bh, acc[rt][ct], 0, 0, 0);
            }
        }
    }

#pragma unroll
    for (int ct = 0; ct < 6; ++ct) {
        const int col = col0 + wc * 96 + ct * 16 + l15;
        const float bec = b_enc[col];
#pragma unroll
        for (int rt = 0; rt < 4; ++rt) {
            const int rowb = row_w + rt * 16 + lc * 4;
#pragma unroll
            for (int r = 0; r < 4; ++r)
                z[(size_t)(rowb + r) * D_SAE + col] = fmaxf(acc[rt][ct][r] + bec, 0.f);
        }
    }
}

// ------------- per-row: 1-pass histogram + reg-candidates, rank-select, sparsify, decode -------------
#define TB     256
#define QPT    (D_SAE / 4 / TB)   // 24
#define HB     2048
#define NCOPY  2
#define BNDCAP 248
#define POOLN  288                // C_SEL + BNDCAP
#define NCAND  6
#define NEGF   -1e30f
#define BADIDX (1 << 30)

__global__ __launch_bounds__(TB, 4)
void sae_topk_decode(float* __restrict__ z,
                     const float* __restrict__ x,
                     const float* __restrict__ W_enc,
                     const float* __restrict__ b_enc,
                     const float* __restrict__ W_dec,
                     const float* __restrict__ b_dec,
                     float* __restrict__ x_rec)
{
    __shared__ int    hist[NCOPY * HB];   // 16 KB
    __shared__ int    sufx[TB];
    __shared__ float  poolv[POOLN];
    __shared__ int    pooli[POOLN];
    __shared__ float  selv[C_SEL];
    __shared__ int    seli[C_SEL];
    __shared__ float  xrow[D_IN];
    __shared__ double cand[C_SEL];
    __shared__ int    shB, shChi;
    __shared__ int    nDef, nBnd, nFail;

    const int row = blockIdx.x;
    const int t   = threadIdx.x;
    const int w   = t >> 6;
    float* zr = z + (size_t)row * D_SAE;

    for (int i = t; i < NCOPY * HB; i += TB) hist[i] = 0;
    if (t == 0) { nDef = 0; nBnd = 0; nFail = 0; }
    __syncthreads();

    // ---- phase 1: single streaming read; histogram + per-thread top-6 candidates ----
    float cv[NCAND]; int ci[NCAND];
#pragma unroll
    for (int j = 0; j < NCAND; ++j) { cv[j] = NEGF; ci[j] = BADIDX; }
    {
        int* hw = &hist[(w >> 1) * HB];
        int zc = 0;
        for (int i0 = 0; i0 < QPT; i0 += 8) {
            f32x4 va[8];
#pragma unroll
            for (int u2 = 0; u2 < 8; ++u2)
                va[u2] = __builtin_nontemporal_load((const f32x4*)(&zr[(size_t)(t + (i0 + u2) * TB) * 4]));
#pragma unroll
            for (int u2 = 0; u2 < 8; ++u2) {
                const int base = (t + (i0 + u2) * TB) * 4;
#define PROC(f, o) { \
        const unsigned uu = __float_as_uint(f); \
        if (uu) atomicAdd(&hw[uu >> 20], 1); else ++zc; \
        const bool b0 = (f) > cv[0]; const bool b1 = (f) > cv[1]; const bool b2 = (f) > cv[2]; \
        const bool b3 = (f) > cv[3]; const bool b4 = (f) > cv[4]; const bool b5 = (f) > cv[5]; \
        if (b5) { \
            cv[5] = b4 ? cv[4] : (f);        ci[5] = b4 ? ci[4] : (base + o); \
            if (b4) { cv[4] = b3 ? cv[3] : (f); ci[4] = b3 ? ci[3] : (base + o); } \
            if (b3) { cv[3] = b2 ? cv[2] : (f); ci[3] = b2 ? ci[2] : (base + o); } \
            if (b2) { cv[2] = b1 ? cv[1] : (f); ci[2] = b1 ? ci[1] : (base + o); } \
            if (b1) { cv[1] = b0 ? cv[0] : (f); ci[1] = b0 ? ci[0] : (base + o); } \
            if (b0) { cv[0] = (f); ci[0] = (base + o); } \
        } }
                PROC(va[u2][0], 0) PROC(va[u2][1], 1) PROC(va[u2][2], 2) PROC(va[u2][3], 3)
#undef PROC
            }
        }
        if (zc) atomicAdd(&hw[0], zc);
    }
    __syncthreads();

    // ---- find threshold bucket B: count(bucket > B) < C_SEL <= count(bucket >= B) ----
    int cnt8[8]; int tot = 0;
#pragma unroll
    for (int j = 0; j < 8; ++j) {
        const int b = t * 8 + j;
        const int c = hist[b] + hist[HB + b];
        cnt8[j] = c; tot += c;
    }
    sufx[t] = tot;
    __syncthreads();
    for (int off = 1; off < TB; off <<= 1) {
        const int a = sufx[t];
        const int b = (t + off < TB) ? sufx[t + off] : 0;
        __syncthreads();
        sufx[t] = a + b;
        __syncthreads();
    }
    {
        int run = (t + 1 < TB) ? sufx[t + 1] : 0;
#pragma unroll
        for (int j = 7; j >= 0; --j) {
            const int c = cnt8[j];
            if (run < C_SEL && run + c >= C_SEL) { shB = t * 8 + j; shChi = run; }
            run += c;
        }
    }
    __syncthreads();
    const int B = shB;

    // ---- fail check: 6th candidate also qualifies -> may have dropped a qualifier ----
    if (cv[NCAND - 1] > 0.f && (int)(__float_as_uint(cv[NCAND - 1]) >> 20) >= B) nFail = 1;
    __syncthreads();

    // ---- collect: defs (bucket > B) and boundary (== B) ----
    if (!nFail) {
#pragma unroll
        for (int j = 0; j < NCAND; ++j) {
            if (cv[j] > 0.f) {
                const int bk = (int)(__float_as_uint(cv[j]) >> 20);
                if (bk > B) {
                    const int p = atomicAdd(&nDef, 1);
                    poolv[p] = cv[j]; pooli[p] = ci[j];
                } else if (bk == B) {
                    const int p = atomicAdd(&nBnd, 1);
                    if (p < BNDCAP) { poolv[C_SEL + p] = cv[j]; pooli[C_SEL + p] = ci[j]; }
                }
            }
        }
    } else {
        for (int i = 0; i < QPT; ++i) {
            const float4 v = *(const float4*)(&zr[(size_t)(t + i * TB) * 4]);
            const int base = (t + i * TB) * 4;
#define COL(f, o) { const unsigned uu = __float_as_uint(f); if (uu) { const int bk = (int)(uu >> 20); \
            if (bk > B) { const int p = atomicAdd(&nDef, 1); poolv[p] = (f); pooli[p] = base + o; } \
            else if (bk == B) { const int p = atomicAdd(&nBnd, 1); if (p < BNDCAP) { poolv[C_SEL + p] = (f); pooli[C_SEL + p] = base + o; } } } }
            COL(v.x, 0) COL(v.y, 1) COL(v.z, 2) COL(v.w, 3)
#undef COL
        }
    }
    __syncthreads();

    // ---- pad pool; init selv ----
    {
        const int ndef  = nDef;
        const int nbndc = (nBnd < BNDCAP) ? nBnd : BNDCAP;
        for (int i = t; i < POOLN; i += TB)
            if (!(i < ndef) && !(i >= C_SEL && i < C_SEL + nbndc)) { poolv[i] = NEGF; pooli[i] = BADIDX; }
        if (t < C_SEL) { selv[t] = NEGF; seli[t] = BADIDX; }
    }
    __syncthreads();

    // ---- rank-based top-40 by (value desc, index asc) ----
    for (int e = t; e < POOLN; e += TB) {
        const float mv = poolv[e]; const int mi = pooli[e];
        int rank = 0;
        for (int j = 0; j < POOLN; ++j) {
            const float vj = poolv[j]; const int ij = pooli[j];
            if (vj > mv || (vj == mv && ij < mi)) ++rank;
        }
        if (rank < C_SEL && mi != BADIDX) { selv[rank] = mv; seli[rank] = mi; }
    }
    __syncthreads();

    // ---- fp64 refine when rank-32/33 boundary is tight ----
    if (selv[K_TOP - 1] - selv[K_TOP] < DELTA) {
        const int l = t & 63;
        for (int k = t; k < D_IN; k += TB) xrow[k] = x[(size_t)row * D_IN + k] - b_dec[k];
        __syncthreads();
        for (int j = w; j < C_SEL; j += 4) {
            const int c = seli[j];
            if (c < D_SAE) {
                double acc = 0.0;
#pragma unroll
                for (int q = 0; q < D_IN / 64; ++q) {
                    const int k = l + q * 64;
                    acc = fma((double)xrow[k], (double)W_enc[(size_t)k * D_SAE + c], acc);
                }
#pragma unroll
                for (int off = 32; off > 0; off >>= 1) acc += __shfl_down(acc, off);
                if (l == 0) {
                    const double vv = acc + (double)b_enc[c];
                    cand[j] = vv > 0.0 ? vv : 0.0;
                }
            } else if (l == 0) cand[j] = -1e300;
        }
        __syncthreads();
        if (t == 0) {
            bool used[C_SEL]; float nv[K_TOP]; int ni[K_TOP];
            for (int j = 0; j < C_SEL; ++j) used[j] = false;
            for (int s = 0; s < K_TOP; ++s) {
                int bj = -1; double bvv = 0.0; int bidx = 0;
                for (int j = 0; j < C_SEL; ++j) {
                    if (used[j]) continue;
                    const double v = cand[j]; const int idx = seli[j];
                    if (bj < 0 || v > bvv || (v == bvv && idx < bidx)) { bj = j; bvv = v; bidx = idx; }
                }
                used[bj] = true; nv[s] = (float)bvv; ni[s] = bidx;
            }
            for (int s = 0; s < K_TOP; ++s) { selv[s] = nv[s]; seli[s] = ni[s]; }
        }
        __syncthreads();
    }

    // ---- write sparse row: zeros + scatter ----
    {
        const f32x4 z4 = (f32x4){0.f, 0.f, 0.f, 0.f};
        for (int i = 0; i < QPT; ++i)
            __builtin_nontemporal_store(z4, (f32x4*)(&zr[(size_t)(t + i * TB) * 4]));
    }
    __syncthreads();
    if (t < K_TOP && seli[t] < D_SAE) zr[seli[t]] = selv[t];

    // ---- decode ----
    float a0 = b_dec[t], a1 = b_dec[t + 256], a2 = b_dec[t + 512];
#pragma unroll 8
    for (int s = 0; s < K_TOP; ++s) {
        if (seli[s] < D_SAE) {
            const float v = selv[s];
            const float* wd = W_dec + (size_t)seli[s] * D_IN;
            a0 = fmaf(v, wd[t],       a0);
            a1 = fmaf(v, wd[t + 256], a1);
            a2 = fmaf(v, wd[t + 512], a2);
        }
    }
    float* xr = x_rec + (size_t)row * D_IN;
    xr[t] = a0; xr[t + 256] = a1; xr[t + 512] = a2;
}

extern "C" void kernel_launch(void* const* d_in, const int* in_sizes, int n_in,
                              void* d_out, int out_size, void* d_ws, size_t ws_size,
                              hipStream_t stream)
{
    const float* x     = (const float*)d_in[0];
    const float* W_enc = (const float*)d_in[1];
    const float* b_enc = (const float*)d_in[2];
    const float* W_dec = (const float*)d_in[3];
    const float* b_dec = (const float*)d_in[4];

    float* out   = (float*)d_out;
    float* x_rec = out;
    float* z     = out + (size_t)N_ROWS * D_IN;

    dim3 g1(D_SAE / GBN, N_ROWS / GBM);
    sae_encode_mfma<<<g1, 256, 0, stream>>>(x, W_enc, b_enc, b_dec, z);
    sae_topk_decode<<<N_ROWS, TB, 0, stream>>>(z, x, W_enc, b_enc, W_dec, b_dec, x_rec);
}